// Round 2
// baseline (652.567 us; speedup 1.0000x reference)
//
#include <hip/hip_runtime.h>
#include <math.h>

// Problem constants
// B=4, C1=128, C2=256, H=W=64, HW=4096, k=3, N=9, offset channels = 18
// ws layout (floats):
//   xp  : [4][256][4096]  = 4194304
//   off : [4][18][4096]   = 294912
//   wT  : [9][256][256]   = 589824   (wT[n][c][o] = dcn_w[o][c][n])
#define XP_OFF 0
#define OFF_OFF 4194304
#define WT_OFF (4194304 + 294912)

// ---------------------------------------------------------------------------
// K0: prep — transpose dcn_w into wT[n][c][o]; init off[b][j][hw] = off_b[j]
// grid 2304 x 256
__global__ __launch_bounds__(256) void k0_prep(const float* __restrict__ dcn,
                                               const float* __restrict__ offb,
                                               float* __restrict__ wT,
                                               float* __restrict__ off) {
    int idx = blockIdx.x * 256 + threadIdx.x;          // 0 .. 589823
    int o = idx & 255, c = (idx >> 8) & 255, n = idx >> 16;
    wT[idx] = dcn[(o * 256 + c) * 9 + n];
    if (idx < 294912) {
        int j = (idx >> 12) % 18;
        off[idx] = offb[j];
    }
}

// ---------------------------------------------------------------------------
// K1: pointwise conv (C1=128 -> C2=256) + BN affine.
// GEMM: xp[b][c2][hw] = sum_k x[b][k][hw] * pw[c2][k], then *scale + shift.
// grid (256 pixel-tiles of 64, 4 c2-tiles of 64) x 256 threads.
__global__ __launch_bounds__(256) void k1_pw_bn(const float* __restrict__ x,
                                                const float* __restrict__ pw,
                                                const float* __restrict__ gamma,
                                                const float* __restrict__ beta,
                                                const float* __restrict__ mean,
                                                const float* __restrict__ var,
                                                float* __restrict__ xp) {
    __shared__ float wl[128 * 64];   // [k][c2_local]
    int t = threadIdx.x;
    int m0 = blockIdx.x * 64;
    int b = m0 >> 12;
    int hw = (m0 & 4095) + (t & 63);
    int q = t >> 6;                  // 0..3, c2 quad
    int c2base = blockIdx.y * 64;

    // stage weights: 64 c2 x 128 k
    for (int i = 0; i < 32; ++i) {
        int idx = t + 256 * i;
        int c2l = idx >> 7, kk = idx & 127;
        wl[kk * 64 + c2l] = pw[(c2base + c2l) * 128 + kk];
    }
    __syncthreads();

    float acc[16];
#pragma unroll
    for (int i = 0; i < 16; ++i) acc[i] = 0.f;

    const float* xb = x + (b * 128) * 4096 + hw;
    for (int kk = 0; kk < 128; ++kk) {
        float xv = xb[kk * 4096];
        const float4* w4 = (const float4*)&wl[kk * 64 + q * 16];
#pragma unroll
        for (int i = 0; i < 4; ++i) {
            float4 wv = w4[i];
            acc[i * 4 + 0] += xv * wv.x;
            acc[i * 4 + 1] += xv * wv.y;
            acc[i * 4 + 2] += xv * wv.z;
            acc[i * 4 + 3] += xv * wv.w;
        }
    }
#pragma unroll
    for (int i = 0; i < 16; ++i) {
        int c2 = c2base + q * 16 + i;
        float s = gamma[c2] * rsqrtf(var[c2] + 1e-5f);
        float sh = beta[c2] - mean[c2] * s;
        xp[(b * 256 + c2) * 4096 + hw] = acc[i] * s + sh;
    }
}

// ---------------------------------------------------------------------------
// K2: 3x3 offset conv (256 -> 18), zero-padded, accumulated via atomicAdd
// (off pre-initialized to bias by K0). One block per (b, h, c-split-half):
// grid 512 x 256. Each block: row of 64 pixels, 128 input channels.
__global__ __launch_bounds__(256) void k2_off(const float* __restrict__ xp,
                                              const float* __restrict__ offw,
                                              float* __restrict__ off) {
    __shared__ float xl[3 * 32 * 66];    // [dy][c][col], col = w+1 (zero-padded)
    __shared__ float wl[9 * 18 * 32];    // [tap][j][c]
    int t = threadIdx.x;
    int bx = blockIdx.x;                 // b*128 + h*2 + cs
    int b = bx >> 7, h = (bx >> 1) & 63, cs = bx & 1;
    int w = t & 63, jset = t >> 6;
    const int jbase_a[4] = {0, 5, 10, 14};
    const int jcnt_a[4] = {5, 5, 4, 4};
    int jbase = jbase_a[jset], jcnt = jcnt_a[jset];
    float acc[5] = {0.f, 0.f, 0.f, 0.f, 0.f};

    for (int ch = 0; ch < 4; ++ch) {
        int cbase = cs * 128 + ch * 32;
        // stage 3 input rows x 32 channels x 66 cols (zero-padded)
        for (int idx = t; idx < 3 * 32 * 66; idx += 256) {
            int dy = idx / 2112, rem = idx % 2112;
            int c = rem / 66, col = rem % 66;
            int y = h + dy - 1, wc = col - 1;
            float v = 0.f;
            if ((unsigned)y < 64u && (unsigned)wc < 64u)
                v = xp[((b * 256 + cbase + c) << 12) + y * 64 + wc];
            xl[idx] = v;
        }
        // stage weights [tap][j][c] (src read coalesced over (c,tap))
        for (int idx = t; idx < 18 * 32 * 9; idx += 256) {
            int j = idx / 288, c = (idx / 9) % 32, tap = idx % 9;
            wl[(tap * 18 + j) * 32 + c] = offw[(j * 256 + cbase + c) * 9 + tap];
        }
        __syncthreads();
#pragma unroll
        for (int tap = 0; tap < 9; ++tap) {
            int dy = tap / 3, dx = tap % 3;
            const float* xrow = &xl[dy * 2112 + (w + dx)];
            const float4* wrow = (const float4*)&wl[(tap * 18 + jbase) * 32];
#pragma unroll
            for (int c4 = 0; c4 < 8; ++c4) {
                float xv0 = xrow[(c4 * 4 + 0) * 66];
                float xv1 = xrow[(c4 * 4 + 1) * 66];
                float xv2 = xrow[(c4 * 4 + 2) * 66];
                float xv3 = xrow[(c4 * 4 + 3) * 66];
#pragma unroll
                for (int jj = 0; jj < 5; ++jj) {
                    if (jj < jcnt) {
                        float4 wv = wrow[jj * 8 + c4];
                        acc[jj] += xv0 * wv.x + xv1 * wv.y + xv2 * wv.z + xv3 * wv.w;
                    }
                }
            }
        }
        __syncthreads();
    }
    for (int jj = 0; jj < 5; ++jj) {
        if (jj < jcnt)
            atomicAdd(&off[((b * 18 + jbase + jj) << 12) + h * 64 + w], acc[jj]);
    }
}

// ---------------------------------------------------------------------------
// K3: deformable bilinear sampling fused with einsum 'bcnhw,ocn->bohw' + SiLU.
// One block = 32 pixels (half row) x all 256 output channels.
// grid 512 x 256. Thread o holds acc[32] (one output channel x 32 pixels).
__global__ __launch_bounds__(256) void k3_dcn(const float* __restrict__ xp,
                                              const float* __restrict__ off,
                                              const float* __restrict__ wT,
                                              float* __restrict__ out) {
    __shared__ int i00[288], i01[288], i10[288], i11[288];
    __shared__ float w00[288], w01[288], w10[288], w11[288];
    __shared__ float samp[32 * 32];      // [c_local][p]
    int t = threadIdx.x;
    int bx = blockIdx.x;                 // b*128 + h*2 + half
    int b = bx >> 7, h = (bx >> 1) & 63, wh = (bx & 1) * 32;

    // phase A: sampling params for 9 taps x 32 pixels
    for (int tt = t; tt < 288; tt += 256) {
        int n = tt >> 5, p = tt & 31;
        int w = wh + p;
        float oy = off[((b * 18 + n) << 12) + h * 64 + w];
        float ox = off[((b * 18 + n + 9) << 12) + h * 64 + w];
        float py = (float)(h + n / 3 - 1) + oy;
        float px = (float)(w + n % 3 - 1) + ox;
        py = fminf(fmaxf(py, 0.f), 63.f);
        px = fminf(fmaxf(px, 0.f), 63.f);
        float fy = floorf(py), fx = floorf(px);
        int y0 = (int)fy, x0 = (int)fx;
        float wy = py - fy, wx = px - fx;
        int y1 = min(y0 + 1, 63), x1 = min(x0 + 1, 63);
        i00[tt] = y0 * 64 + x0;
        i01[tt] = y0 * 64 + x1;
        i10[tt] = y1 * 64 + x0;
        i11[tt] = y1 * 64 + x1;
        w00[tt] = (1.f - wy) * (1.f - wx);
        w01[tt] = (1.f - wy) * wx;
        w10[tt] = wy * (1.f - wx);
        w11[tt] = wy * wx;
    }
    __syncthreads();

    float acc[32];
#pragma unroll
    for (int i = 0; i < 32; ++i) acc[i] = 0.f;
    int o = t;
    int cl = t >> 5, p = t & 31;         // gather role: 8 c-lanes x 32 pixels

    for (int n = 0; n < 9; ++n) {
        int sb = n * 32 + p;
        int a00 = i00[sb], a01 = i01[sb], a10 = i10[sb], a11 = i11[sb];
        float b00 = w00[sb], b01 = w01[sb], b10 = w10[sb], b11 = w11[sb];
        for (int cc = 0; cc < 8; ++cc) {
            __syncthreads();             // samp reuse across iterations
#pragma unroll
            for (int ii = 0; ii < 4; ++ii) {
                int c = cc * 32 + ii * 8 + cl;
                const float* base = xp + ((b * 256 + c) << 12);
                samp[(ii * 8 + cl) * 32 + p] =
                    b00 * base[a00] + b01 * base[a01] + b10 * base[a10] + b11 * base[a11];
            }
            __syncthreads();
            const float* wb = wT + (n * 256 + cc * 32) * 256 + o;
#pragma unroll
            for (int c2 = 0; c2 < 32; ++c2) {
                float wv = wb[c2 * 256];
                const float4* sp = (const float4*)&samp[c2 * 32];
#pragma unroll
                for (int p4 = 0; p4 < 8; ++p4) {
                    float4 sv = sp[p4];
                    acc[p4 * 4 + 0] += wv * sv.x;
                    acc[p4 * 4 + 1] += wv * sv.y;
                    acc[p4 * 4 + 2] += wv * sv.z;
                    acc[p4 * 4 + 3] += wv * sv.w;
                }
            }
        }
    }

    // epilogue: SiLU + coalesced-per-thread float4 stores
    float* ob = out + ((b * 256 + o) << 12) + h * 64 + wh;
#pragma unroll
    for (int p4 = 0; p4 < 8; ++p4) {
        float a0 = acc[p4 * 4 + 0], a1 = acc[p4 * 4 + 1];
        float a2 = acc[p4 * 4 + 2], a3 = acc[p4 * 4 + 3];
        float4 v;
        v.x = a0 / (1.f + expf(-a0));
        v.y = a1 / (1.f + expf(-a1));
        v.z = a2 / (1.f + expf(-a2));
        v.w = a3 / (1.f + expf(-a3));
        ((float4*)ob)[p4] = v;
    }
}

// ---------------------------------------------------------------------------
extern "C" void kernel_launch(void* const* d_in, const int* in_sizes, int n_in,
                              void* d_out, int out_size, void* d_ws, size_t ws_size,
                              hipStream_t stream) {
    const float* x     = (const float*)d_in[0];
    const float* pw    = (const float*)d_in[1];
    const float* gamma = (const float*)d_in[2];
    const float* beta  = (const float*)d_in[3];
    const float* mean  = (const float*)d_in[4];
    const float* var   = (const float*)d_in[5];
    const float* offw  = (const float*)d_in[6];
    const float* offb  = (const float*)d_in[7];
    const float* dcn   = (const float*)d_in[8];
    float* ws  = (float*)d_ws;
    float* xp  = ws + XP_OFF;
    float* off = ws + OFF_OFF;
    float* wT  = ws + WT_OFF;
    float* out = (float*)d_out;

    hipLaunchKernelGGL(k0_prep, dim3(2304), dim3(256), 0, stream, dcn, offb, wT, off);
    hipLaunchKernelGGL(k1_pw_bn, dim3(256, 4), dim3(256), 0, stream,
                       x, pw, gamma, beta, mean, var, xp);
    hipLaunchKernelGGL(k2_off, dim3(512), dim3(256), 0, stream, xp, offw, off);
    hipLaunchKernelGGL(k3_dcn, dim3(512), dim3(256), 0, stream, xp, off, wT, out);
}

// Round 3
// 331.577 us; speedup vs baseline: 1.9681x; 1.9681x over previous
//
#include <hip/hip_runtime.h>
#include <math.h>

// B=4, C1=128, C2=256, H=W=64, HW=4096, k=3, N=9
// ws layout (float units):
//   xp   : [4][256][4096] f32          @ 0          (4194304 f32)
//   off  : [4][18][4096]  f32          @ 4194304    (294912 f32)
//   xpb  : [4][256][4096] bf16         @ 4489216    (2097152 f32-slots)
//   wTb  : [9][256o][256c] bf16        @ 6586368    (294912 f32-slots)
#define XP_F   0
#define OFF_F  4194304
#define XPB_F  4489216
#define WTB_F  6586368

typedef short bf16x8 __attribute__((ext_vector_type(8)));
typedef float f32x4 __attribute__((ext_vector_type(4)));

__device__ inline unsigned short f2b(float f) {
    union { float f; unsigned u; } v; v.f = f;
    unsigned r = v.u + 0x7FFF + ((v.u >> 16) & 1);   // RNE
    return (unsigned short)(r >> 16);
}
__device__ inline float b2f(unsigned short h) {
    union { unsigned u; float f; } v; v.u = ((unsigned)h) << 16; return v.f;
}

// ---------------------------------------------------------------------------
// K0: wTb[n][o][c] = bf16(dcn[o][c][n]); off init to bias. grid 2304 x 256
__global__ __launch_bounds__(256) void k0_prep(const float* __restrict__ dcn,
                                               const float* __restrict__ offb,
                                               unsigned short* __restrict__ wTb,
                                               float* __restrict__ off) {
    int idx = blockIdx.x * 256 + threadIdx.x;          // 0 .. 589823
    int n = idx >> 16, o = (idx >> 8) & 255, c = idx & 255;
    wTb[idx] = f2b(dcn[(o * 256 + c) * 9 + n]);
    if (idx < 294912) {
        int j = (idx >> 12) % 18;
        off[idx] = offb[j];
    }
}

// ---------------------------------------------------------------------------
// K1: pointwise conv (128->256) + BN; writes xp (f32, for K2) and xpb (bf16, K3).
__global__ __launch_bounds__(256) void k1_pw_bn(const float* __restrict__ x,
                                                const float* __restrict__ pw,
                                                const float* __restrict__ gamma,
                                                const float* __restrict__ beta,
                                                const float* __restrict__ mean,
                                                const float* __restrict__ var,
                                                float* __restrict__ xp,
                                                unsigned short* __restrict__ xpb) {
    __shared__ float wl[128 * 64];   // [k][c2_local]
    int t = threadIdx.x;
    int m0 = blockIdx.x * 64;
    int b = m0 >> 12;
    int hw = (m0 & 4095) + (t & 63);
    int q = t >> 6;
    int c2base = blockIdx.y * 64;

    for (int i = 0; i < 32; ++i) {
        int idx = t + 256 * i;
        int c2l = idx >> 7, kk = idx & 127;
        wl[kk * 64 + c2l] = pw[(c2base + c2l) * 128 + kk];
    }
    __syncthreads();

    float acc[16];
#pragma unroll
    for (int i = 0; i < 16; ++i) acc[i] = 0.f;

    const float* xb = x + (b * 128) * 4096 + hw;
    for (int kk = 0; kk < 128; ++kk) {
        float xv = xb[kk * 4096];
        const float4* w4 = (const float4*)&wl[kk * 64 + q * 16];
#pragma unroll
        for (int i = 0; i < 4; ++i) {
            float4 wv = w4[i];
            acc[i * 4 + 0] += xv * wv.x;
            acc[i * 4 + 1] += xv * wv.y;
            acc[i * 4 + 2] += xv * wv.z;
            acc[i * 4 + 3] += xv * wv.w;
        }
    }
#pragma unroll
    for (int i = 0; i < 16; ++i) {
        int c2 = c2base + q * 16 + i;
        float s = gamma[c2] * rsqrtf(var[c2] + 1e-5f);
        float v = acc[i] * s + (beta[c2] - mean[c2] * s);
        int a = ((b * 256 + c2) << 12) + hw;
        xp[a] = v;
        xpb[a] = f2b(v);
    }
}

// ---------------------------------------------------------------------------
// K2: 3x3 offset conv (256 -> 18) via atomicAdd, one 32-channel slice/block.
// grid 2048 x 256: bx = b*512 + h*8 + cs
__global__ __launch_bounds__(256) void k2_off(const float* __restrict__ xp,
                                              const float* __restrict__ offw,
                                              float* __restrict__ off) {
    __shared__ float xl[3 * 32 * 66];
    __shared__ float wl[9 * 18 * 32];
    int t = threadIdx.x;
    int bx = blockIdx.x;
    int b = bx >> 9, h = (bx >> 3) & 63, cs = bx & 7;
    int w = t & 63, jset = t >> 6;
    const int jbase_a[4] = {0, 5, 10, 14};
    const int jcnt_a[4] = {5, 5, 4, 4};
    int jbase = jbase_a[jset], jcnt = jcnt_a[jset];
    float acc[5] = {0.f, 0.f, 0.f, 0.f, 0.f};
    int cbase = cs * 32;

    for (int idx = t; idx < 3 * 32 * 66; idx += 256) {
        int dy = idx / 2112, rem = idx % 2112;
        int c = rem / 66, col = rem % 66;
        int y = h + dy - 1, wc = col - 1;
        float v = 0.f;
        if ((unsigned)y < 64u && (unsigned)wc < 64u)
            v = xp[((b * 256 + cbase + c) << 12) + y * 64 + wc];
        xl[idx] = v;
    }
    for (int idx = t; idx < 18 * 32 * 9; idx += 256) {
        int j = idx / 288, c = (idx / 9) % 32, tap = idx % 9;
        wl[(tap * 18 + j) * 32 + c] = offw[(j * 256 + cbase + c) * 9 + tap];
    }
    __syncthreads();
#pragma unroll
    for (int tap = 0; tap < 9; ++tap) {
        int dy = tap / 3, dx = tap % 3;
        const float* xrow = &xl[dy * 2112 + (w + dx)];
        const float4* wrow = (const float4*)&wl[(tap * 18 + jbase) * 32];
#pragma unroll
        for (int c4 = 0; c4 < 8; ++c4) {
            float xv0 = xrow[(c4 * 4 + 0) * 66];
            float xv1 = xrow[(c4 * 4 + 1) * 66];
            float xv2 = xrow[(c4 * 4 + 2) * 66];
            float xv3 = xrow[(c4 * 4 + 3) * 66];
#pragma unroll
            for (int jj = 0; jj < 5; ++jj) {
                if (jj < jcnt) {
                    float4 wv = wrow[jj * 8 + c4];
                    acc[jj] += xv0 * wv.x + xv1 * wv.y + xv2 * wv.z + xv3 * wv.w;
                }
            }
        }
    }
    for (int jj = 0; jj < 5; ++jj) {
        if (jj < jcnt)
            atomicAdd(&off[((b * 18 + jbase + jj) << 12) + h * 64 + w], acc[jj]);
    }
}

// ---------------------------------------------------------------------------
// K3: deformable sampling fused with bf16-MFMA einsum + SiLU.
// Block: 512 thr = 8 waves; tile 32 px x 256 o; wave tile 32 o x 32 px.
// K-loop: 72 phases (9 n x 8 c-slices of 32), double-buffered samp LDS.
// grid 512: bx = b*128 + h*2 + half
__global__ __launch_bounds__(512) void k3_dcn(const unsigned short* __restrict__ xpb,
                                              const float* __restrict__ off,
                                              const unsigned short* __restrict__ wTb,
                                              float* __restrict__ out) {
    __shared__ int   i00[288], i01[288], i10[288], i11[288];
    __shared__ float w00[288], w01[288], w10[288], w11[288];
    __shared__ unsigned short smp[2][32 * 40];   // [buf][px][32c], row stride 80B

    int t = threadIdx.x;
    int bx = blockIdx.x;
    int b = bx >> 7, h = (bx >> 1) & 63, wh = (bx & 1) * 32;
    int wv = t >> 6, l = t & 63;

    // sampling params: 9 taps x 32 px
    if (t < 288) {
        int n = t >> 5, p = t & 31;
        int w = wh + p;
        float oy = off[((b * 18 + n) << 12) + h * 64 + w];
        float ox = off[((b * 18 + n + 9) << 12) + h * 64 + w];
        float py = (float)(h + n / 3 - 1) + oy;
        float px = (float)(w + n % 3 - 1) + ox;
        py = fminf(fmaxf(py, 0.f), 63.f);
        px = fminf(fmaxf(px, 0.f), 63.f);
        float fy = floorf(py), fx = floorf(px);
        int y0 = (int)fy, x0 = (int)fx;
        float wy = py - fy, wx = px - fx;
        int y1 = min(y0 + 1, 63), x1 = min(x0 + 1, 63);
        i00[t] = y0 * 64 + x0;  i01[t] = y0 * 64 + x1;
        i10[t] = y1 * 64 + x0;  i11[t] = y1 * 64 + x1;
        w00[t] = (1.f - wy) * (1.f - wx);  w01[t] = (1.f - wy) * wx;
        w10[t] = wy * (1.f - wx);          w11[t] = wy * wx;
    }
    __syncthreads();

    int ppx = t & 31;                 // produce: pixel
    int c0 = wv * 4 + ((t >> 5) & 1) * 2;   // produce: local c pair base (0..30)

    auto produce = [&](int p) {
        int n = p >> 3, cc = p & 7, bu = p & 1;
        int sb = n * 32 + ppx;
        int a00 = i00[sb], a01 = i01[sb], a10 = i10[sb], a11 = i11[sb];
        float b00 = w00[sb], b01 = w01[sb], b10 = w10[sb], b11 = w11[sb];
        unsigned pack = 0;
#pragma unroll
        for (int i = 0; i < 2; ++i) {
            const unsigned short* base = xpb + ((b * 256 + cc * 32 + c0 + i) << 12);
            float v = b00 * b2f(base[a00]) + b01 * b2f(base[a01]) +
                      b10 * b2f(base[a10]) + b11 * b2f(base[a11]);
            pack |= ((unsigned)f2b(v)) << (16 * i);
        }
        ((unsigned*)smp[bu])[ppx * 20 + (c0 >> 1)] = pack;
    };

    produce(0);

    f32x4 acc[2][2];
#pragma unroll
    for (int i = 0; i < 2; ++i)
#pragma unroll
        for (int j = 0; j < 2; ++j) acc[i][j] = (f32x4)0.f;

    int arow = (l & 15), ak = (l >> 4) * 8;
    for (int p = 0; p < 72; ++p) {
        __syncthreads();
        if (p < 71) produce(p + 1);
        int n = p >> 3, cc = p & 7, bu = p & 1;
        const unsigned short* wb = wTb + (n * 256 + wv * 32 + arow) * 256 + cc * 32 + ak;
        bf16x8 a0 = *(const bf16x8*)wb;
        bf16x8 a1 = *(const bf16x8*)(wb + 16 * 256);
#pragma unroll
        for (int pt = 0; pt < 2; ++pt) {
            bf16x8 bfr = *(const bf16x8*)&smp[bu][(pt * 16 + (l & 15)) * 40 + (l >> 4) * 8];
            acc[0][pt] = __builtin_amdgcn_mfma_f32_16x16x32_bf16(a0, bfr, acc[0][pt], 0, 0, 0);
            acc[1][pt] = __builtin_amdgcn_mfma_f32_16x16x32_bf16(a1, bfr, acc[1][pt], 0, 0, 0);
        }
    }

    // epilogue: SiLU + store. D: row(o) = (l>>4)*4+j, col(px) = l&15
#pragma unroll
    for (int ot = 0; ot < 2; ++ot)
#pragma unroll
        for (int pt = 0; pt < 2; ++pt) {
            int px = wh + pt * 16 + (l & 15);
#pragma unroll
            for (int j = 0; j < 4; ++j) {
                int o = wv * 32 + ot * 16 + (l >> 4) * 4 + j;
                float a = acc[ot][pt][j];
                out[((b * 256 + o) << 12) + h * 64 + px] = a / (1.f + expf(-a));
            }
        }
}

// ---------------------------------------------------------------------------
extern "C" void kernel_launch(void* const* d_in, const int* in_sizes, int n_in,
                              void* d_out, int out_size, void* d_ws, size_t ws_size,
                              hipStream_t stream) {
    const float* x     = (const float*)d_in[0];
    const float* pw    = (const float*)d_in[1];
    const float* gamma = (const float*)d_in[2];
    const float* beta  = (const float*)d_in[3];
    const float* mean  = (const float*)d_in[4];
    const float* var   = (const float*)d_in[5];
    const float* offw  = (const float*)d_in[6];
    const float* offb  = (const float*)d_in[7];
    const float* dcn   = (const float*)d_in[8];
    float* ws = (float*)d_ws;
    float* xp  = ws + XP_F;
    float* off = ws + OFF_F;
    unsigned short* xpb = (unsigned short*)(ws + XPB_F);
    unsigned short* wTb = (unsigned short*)(ws + WTB_F);
    float* out = (float*)d_out;

    hipLaunchKernelGGL(k0_prep, dim3(2304), dim3(256), 0, stream, dcn, offb, wTb, off);
    hipLaunchKernelGGL(k1_pw_bn, dim3(256, 4), dim3(256), 0, stream,
                       x, pw, gamma, beta, mean, var, xp, xpb);
    hipLaunchKernelGGL(k2_off, dim3(2048), dim3(256), 0, stream, xp, offw, off);
    hipLaunchKernelGGL(k3_dcn, dim3(512), dim3(512), 0, stream, xpb, off, wTb, out);
}

// Round 5
// 264.389 us; speedup vs baseline: 2.4682x; 1.2541x over previous
//
#include <hip/hip_runtime.h>
#include <math.h>

// B=4, C1=128, C2=256, H=W=64, HW=4096, k=3, N=9
// ws layout (float units):
//   xp   : [4][256][4096] f32  (CHW, for K2)     @ 0          (4194304 f32)
//   off  : [4][18][4096]  f32                    @ 4194304    (294912 f32)
//   xph  : [4][4096][256] bf16 (HWC, for K3)     @ 4489216    (2097152 f32-slots)
//   wTb  : [9][256o][256c] bf16                  @ 6586368    (294912 f32-slots)
#define XP_F   0
#define OFF_F  4194304
#define XPH_F  4489216
#define WTB_F  6586368

typedef short bf16x8 __attribute__((ext_vector_type(8)));
typedef float f32x4 __attribute__((ext_vector_type(4)));

__device__ inline unsigned short f2b(float f) {
    union { float f; unsigned u; } v; v.f = f;
    unsigned r = v.u + 0x7FFF + ((v.u >> 16) & 1);   // RNE
    return (unsigned short)(r >> 16);
}
__device__ inline float b2f(unsigned short h) {
    union { unsigned u; float f; } v; v.u = ((unsigned)h) << 16; return v.f;
}

// ---------------------------------------------------------------------------
// K0: wTb[n][o][c] = bf16(dcn[o][c][n]); off init to bias. grid 2304 x 256
__global__ __launch_bounds__(256) void k0_prep(const float* __restrict__ dcn,
                                               const float* __restrict__ offb,
                                               unsigned short* __restrict__ wTb,
                                               float* __restrict__ off) {
    int idx = blockIdx.x * 256 + threadIdx.x;          // 0 .. 589823
    int n = idx >> 16, o = (idx >> 8) & 255, c = idx & 255;
    wTb[idx] = f2b(dcn[(o * 256 + c) * 9 + n]);
    if (idx < 294912) {
        int j = (idx >> 12) % 18;
        off[idx] = offb[j];
    }
}

// ---------------------------------------------------------------------------
// K1: pointwise conv (128->256) + BN; writes xp (f32 CHW, K2) and xph (bf16 HWC, K3).
__global__ __launch_bounds__(256) void k1_pw_bn(const float* __restrict__ x,
                                                const float* __restrict__ pw,
                                                const float* __restrict__ gamma,
                                                const float* __restrict__ beta,
                                                const float* __restrict__ mean,
                                                const float* __restrict__ var,
                                                float* __restrict__ xp,
                                                unsigned short* __restrict__ xph) {
    __shared__ float wl[128 * 64];   // [k][c2_local]
    int t = threadIdx.x;
    int m0 = blockIdx.x * 64;
    int b = m0 >> 12;
    int hw = (m0 & 4095) + (t & 63);
    int q = t >> 6;
    int c2base = blockIdx.y * 64;

    for (int i = 0; i < 32; ++i) {
        int idx = t + 256 * i;
        int c2l = idx >> 7, kk = idx & 127;
        wl[kk * 64 + c2l] = pw[(c2base + c2l) * 128 + kk];
    }
    __syncthreads();

    float acc[16];
#pragma unroll
    for (int i = 0; i < 16; ++i) acc[i] = 0.f;

    const float* xb = x + (b * 128) * 4096 + hw;
    for (int kk = 0; kk < 128; ++kk) {
        float xv = xb[kk * 4096];
        const float4* w4 = (const float4*)&wl[kk * 64 + q * 16];
#pragma unroll
        for (int i = 0; i < 4; ++i) {
            float4 wv = w4[i];
            acc[i * 4 + 0] += xv * wv.x;
            acc[i * 4 + 1] += xv * wv.y;
            acc[i * 4 + 2] += xv * wv.z;
            acc[i * 4 + 3] += xv * wv.w;
        }
    }
    bf16x8 r0, r1;
#pragma unroll
    for (int i = 0; i < 16; ++i) {
        int c2 = c2base + q * 16 + i;
        float s = gamma[c2] * rsqrtf(var[c2] + 1e-5f);
        float v = acc[i] * s + (beta[c2] - mean[c2] * s);
        xp[((b * 256 + c2) << 12) + hw] = v;
        if (i < 8) r0[i] = (short)f2b(v); else r1[i - 8] = (short)f2b(v);
    }
    unsigned short* hb = xph + (((b << 12) + hw) << 8) + c2base + q * 16;
    *(bf16x8*)hb = r0;
    *(bf16x8*)(hb + 8) = r1;
}

// ---------------------------------------------------------------------------
// K2: 3x3 offset conv (256 -> 18) via atomicAdd, one 32-channel slice/block.
// grid 2048 x 256: bx = b*512 + h*8 + cs
__global__ __launch_bounds__(256) void k2_off(const float* __restrict__ xp,
                                              const float* __restrict__ offw,
                                              float* __restrict__ off) {
    __shared__ float xl[3 * 32 * 66];
    __shared__ float wl[9 * 18 * 32];
    int t = threadIdx.x;
    int bx = blockIdx.x;
    int b = bx >> 9, h = (bx >> 3) & 63, cs = bx & 7;
    int w = t & 63, jset = t >> 6;
    const int jbase_a[4] = {0, 5, 10, 14};
    const int jcnt_a[4] = {5, 5, 4, 4};
    int jbase = jbase_a[jset], jcnt = jcnt_a[jset];
    float acc[5] = {0.f, 0.f, 0.f, 0.f, 0.f};
    int cbase = cs * 32;

    for (int idx = t; idx < 3 * 32 * 66; idx += 256) {
        int dy = idx / 2112, rem = idx % 2112;
        int c = rem / 66, col = rem % 66;
        int y = h + dy - 1, wc = col - 1;
        float v = 0.f;
        if ((unsigned)y < 64u && (unsigned)wc < 64u)
            v = xp[((b * 256 + cbase + c) << 12) + y * 64 + wc];
        xl[idx] = v;
    }
    for (int idx = t; idx < 18 * 32 * 9; idx += 256) {
        int j = idx / 288, c = (idx / 9) % 32, tap = idx % 9;
        wl[(tap * 18 + j) * 32 + c] = offw[(j * 256 + cbase + c) * 9 + tap];
    }
    __syncthreads();
#pragma unroll
    for (int tap = 0; tap < 9; ++tap) {
        int dy = tap / 3, dx = tap % 3;
        const float* xrow = &xl[dy * 2112 + (w + dx)];
        const float4* wrow = (const float4*)&wl[(tap * 18 + jbase) * 32];
#pragma unroll
        for (int c4 = 0; c4 < 8; ++c4) {
            float xv0 = xrow[(c4 * 4 + 0) * 66];
            float xv1 = xrow[(c4 * 4 + 1) * 66];
            float xv2 = xrow[(c4 * 4 + 2) * 66];
            float xv3 = xrow[(c4 * 4 + 3) * 66];
#pragma unroll
            for (int jj = 0; jj < 5; ++jj) {
                if (jj < jcnt) {
                    float4 wv = wrow[jj * 8 + c4];
                    acc[jj] += xv0 * wv.x + xv1 * wv.y + xv2 * wv.z + xv3 * wv.w;
                }
            }
        }
    }
    for (int jj = 0; jj < 5; ++jj) {
        if (jj < jcnt)
            atomicAdd(&off[((b * 18 + jbase + jj) << 12) + h * 64 + w], acc[jj]);
    }
}

// ---------------------------------------------------------------------------
// K3: deformable sampling (HWC coalesced gathers) + bf16 MFMA einsum + SiLU.
// Block: 512 thr = 8 waves; tile 32 px x 256 o; wave tile 32 o x 32 px.
// 9 phases (one per tap); samp tile 32px x 256c bf16, double-buffered,
// 16B-chunk XOR swizzle. grid 512, XCD-bijective swizzled.
__global__ __launch_bounds__(512) void k3_dcn(const unsigned short* __restrict__ xph,
                                              const float* __restrict__ off,
                                              const unsigned short* __restrict__ wTb,
                                              float* __restrict__ out) {
    __shared__ int   i00[288], i01[288], i10[288], i11[288];
    __shared__ float w00[288], w01[288], w10[288], w11[288];
    __shared__ unsigned short smp[2][32 * 256];  // [buf][px][c], XOR-swizzled chunks

    int t = threadIdx.x;
    int orig = blockIdx.x;
    int bx = (orig & 7) * 64 + (orig >> 3);      // XCD-bijective swizzle (512%8==0)
    int b = bx >> 7, h = (bx >> 1) & 63, wh = (bx & 1) * 32;
    int wv = t >> 6, l = t & 63;
    const unsigned short* xb = xph + (b << 20);  // batch base (HWC)

    // phase A: sampling params for 9 taps x 32 px; store loc<<8 (ushort offset)
    if (t < 288) {
        int n = t >> 5, p = t & 31;
        int w = wh + p;
        float oy = off[((b * 18 + n) << 12) + h * 64 + w];
        float ox = off[((b * 18 + n + 9) << 12) + h * 64 + w];
        float py = (float)(h + n / 3 - 1) + oy;
        float px = (float)(w + n % 3 - 1) + ox;
        py = fminf(fmaxf(py, 0.f), 63.f);
        px = fminf(fmaxf(px, 0.f), 63.f);
        float fy = floorf(py), fx = floorf(px);
        int y0 = (int)fy, x0 = (int)fx;
        float wy = py - fy, wx = px - fx;
        int y1 = min(y0 + 1, 63), x1 = min(x0 + 1, 63);
        i00[t] = (y0 * 64 + x0) << 8;  i01[t] = (y0 * 64 + x1) << 8;
        i10[t] = (y1 * 64 + x0) << 8;  i11[t] = (y1 * 64 + x1) << 8;
        w00[t] = (1.f - wy) * (1.f - wx);  w01[t] = (1.f - wy) * wx;
        w10[t] = wy * (1.f - wx);          w11[t] = wy * wx;
    }
    __syncthreads();

    // producer: 2 units/thread; unit -> (px, cg): 32 lanes = one corner burst 512B
    auto produce = [&](int tap) {
        int bu = tap & 1;
#pragma unroll
        for (int k = 0; k < 2; ++k) {
            int unit = t + k * 512;
            int px = unit >> 5, cg = unit & 31;
            int sb = tap * 32 + px;
            int c = cg << 3;
            bf16x8 v00 = *(const bf16x8*)(xb + i00[sb] + c);
            bf16x8 v01 = *(const bf16x8*)(xb + i01[sb] + c);
            bf16x8 v10 = *(const bf16x8*)(xb + i10[sb] + c);
            bf16x8 v11 = *(const bf16x8*)(xb + i11[sb] + c);
            float b00 = w00[sb], b01 = w01[sb], b10 = w10[sb], b11 = w11[sb];
            bf16x8 r;
#pragma unroll
            for (int j = 0; j < 8; ++j) {
                float v = b00 * b2f((unsigned short)v00[j]) +
                          b01 * b2f((unsigned short)v01[j]) +
                          b10 * b2f((unsigned short)v10[j]) +
                          b11 * b2f((unsigned short)v11[j]);
                r[j] = (short)f2b(v);
            }
            *(bf16x8*)&smp[bu][(px << 8) + ((cg ^ (px & 7)) << 3)] = r;
        }
    };

    produce(0);

    f32x4 acc[2][2];
#pragma unroll
    for (int i = 0; i < 2; ++i)
#pragma unroll
        for (int j = 0; j < 2; ++j) acc[i][j] = (f32x4)0.f;

    int arow = l & 15, areg = l >> 4;            // A: row=o (l&15), k-reg group
    for (int tap = 0; tap < 9; ++tap) {
        __syncthreads();
        if (tap < 8) produce(tap + 1);
        int bu = tap & 1;
        const unsigned short* wbase =
            wTb + (tap * 256 + wv * 32 + arow) * 256 + areg * 8;
#pragma unroll
        for (int ks = 0; ks < 8; ++ks) {
            bf16x8 a0 = *(const bf16x8*)(wbase + ks * 32);
            bf16x8 a1 = *(const bf16x8*)(wbase + 16 * 256 + ks * 32);
            int chunk = ks * 4 + areg;
#pragma unroll
            for (int pt = 0; pt < 2; ++pt) {
                int px = pt * 16 + arow;
                bf16x8 bfr = *(const bf16x8*)
                    &smp[bu][(px << 8) + ((chunk ^ (px & 7)) << 3)];
                acc[0][pt] = __builtin_amdgcn_mfma_f32_16x16x32_bf16(a0, bfr, acc[0][pt], 0, 0, 0);
                acc[1][pt] = __builtin_amdgcn_mfma_f32_16x16x32_bf16(a1, bfr, acc[1][pt], 0, 0, 0);
            }
        }
    }

    // epilogue: SiLU + store. D: row(o) = (l>>4)*4+j, col(px) = l&15
#pragma unroll
    for (int ot = 0; ot < 2; ++ot)
#pragma unroll
        for (int pt = 0; pt < 2; ++pt) {
            int px = wh + pt * 16 + (l & 15);
#pragma unroll
            for (int j = 0; j < 4; ++j) {
                int o = wv * 32 + ot * 16 + (l >> 4) * 4 + j;
                float a = acc[ot][pt][j];
                out[((b * 256 + o) << 12) + h * 64 + px] = a / (1.f + expf(-a));
            }
        }
}

// ---------------------------------------------------------------------------
extern "C" void kernel_launch(void* const* d_in, const int* in_sizes, int n_in,
                              void* d_out, int out_size, void* d_ws, size_t ws_size,
                              hipStream_t stream) {
    const float* x     = (const float*)d_in[0];
    const float* pw    = (const float*)d_in[1];
    const float* gamma = (const float*)d_in[2];
    const float* beta  = (const float*)d_in[3];
    const float* mean  = (const float*)d_in[4];
    const float* var   = (const float*)d_in[5];
    const float* offw  = (const float*)d_in[6];
    const float* offb  = (const float*)d_in[7];
    const float* dcn   = (const float*)d_in[8];
    float* ws = (float*)d_ws;
    float* xp  = ws + XP_F;
    float* off = ws + OFF_F;
    unsigned short* xph = (unsigned short*)(ws + XPH_F);
    unsigned short* wTb = (unsigned short*)(ws + WTB_F);
    float* out = (float*)d_out;

    hipLaunchKernelGGL(k0_prep, dim3(2304), dim3(256), 0, stream, dcn, offb, wTb, off);
    hipLaunchKernelGGL(k1_pw_bn, dim3(256, 4), dim3(256), 0, stream,
                       x, pw, gamma, beta, mean, var, xp, xph);
    hipLaunchKernelGGL(k2_off, dim3(2048), dim3(256), 0, stream, xp, offw, off);
    hipLaunchKernelGGL(k3_dcn, dim3(512), dim3(512), 0, stream, xph, off, wTb, out);
}

// Round 6
// 258.246 us; speedup vs baseline: 2.5269x; 1.0238x over previous
//
#include <hip/hip_runtime.h>
#include <math.h>

// B=4, C1=128, C2=256, H=W=64, HW=4096, k=3, N=9
// ws layout (float units):
//   xp   : [4][256][4096] f32  (CHW, for K2)     @ 0          (4194304 f32)
//   off  : [4][18][4096]  f32                    @ 4194304    (294912 f32)
//   xph  : [4][4096][256] bf16 (HWC, for K3)     @ 4489216    (2097152 f32-slots)
//   wTb  : [9][256o][256c] bf16                  @ 6586368    (294912 f32-slots)
#define XP_F   0
#define OFF_F  4194304
#define XPH_F  4489216
#define WTB_F  6586368

typedef short bf16x8 __attribute__((ext_vector_type(8)));
typedef float f32x4 __attribute__((ext_vector_type(4)));

__device__ inline unsigned short f2b(float f) {
    union { float f; unsigned u; } v; v.f = f;
    unsigned r = v.u + 0x7FFF + ((v.u >> 16) & 1);   // RNE
    return (unsigned short)(r >> 16);
}
__device__ inline float b2f(unsigned short h) {
    union { unsigned u; float f; } v; v.u = ((unsigned)h) << 16; return v.f;
}

// ---------------------------------------------------------------------------
// K0: wTb[n][o][c] = bf16(dcn[o][c][n]); off init to bias. grid 2304 x 256
__global__ __launch_bounds__(256) void k0_prep(const float* __restrict__ dcn,
                                               const float* __restrict__ offb,
                                               unsigned short* __restrict__ wTb,
                                               float* __restrict__ off) {
    int idx = blockIdx.x * 256 + threadIdx.x;          // 0 .. 589823
    int n = idx >> 16, o = (idx >> 8) & 255, c = idx & 255;
    wTb[idx] = f2b(dcn[(o * 256 + c) * 9 + n]);
    if (idx < 294912) {
        int j = (idx >> 12) % 18;
        off[idx] = offb[j];
    }
}

// ---------------------------------------------------------------------------
// K1: pointwise conv (128->256) + BN; writes xp (f32 CHW, K2) and xph (bf16 HWC, K3).
// launch_bounds (256,4): grid 1024 = 4 blocks/CU = 4 waves/SIMD -> VGPR cap 128.
__global__ __launch_bounds__(256, 4) void k1_pw_bn(const float* __restrict__ x,
                                                   const float* __restrict__ pw,
                                                   const float* __restrict__ gamma,
                                                   const float* __restrict__ beta,
                                                   const float* __restrict__ mean,
                                                   const float* __restrict__ var,
                                                   float* __restrict__ xp,
                                                   unsigned short* __restrict__ xph) {
    __shared__ float wl[128 * 64];   // [k][c2_local]
    int t = threadIdx.x;
    int m0 = blockIdx.x * 64;
    int b = m0 >> 12;
    int hw = (m0 & 4095) + (t & 63);
    int q = t >> 6;
    int c2base = blockIdx.y * 64;

    for (int i = 0; i < 32; ++i) {
        int idx = t + 256 * i;
        int c2l = idx >> 7, kk = idx & 127;
        wl[kk * 64 + c2l] = pw[(c2base + c2l) * 128 + kk];
    }
    __syncthreads();

    float acc[16];
#pragma unroll
    for (int i = 0; i < 16; ++i) acc[i] = 0.f;

    const float* xb = x + (b * 128) * 4096 + hw;
    for (int kk = 0; kk < 128; kk += 8) {
        float xv[8];
#pragma unroll
        for (int u = 0; u < 8; ++u) xv[u] = xb[(kk + u) * 4096];
#pragma unroll
        for (int u = 0; u < 8; ++u) {
            const float4* w4 = (const float4*)&wl[(kk + u) * 64 + q * 16];
#pragma unroll
            for (int i = 0; i < 4; ++i) {
                float4 wv = w4[i];
                acc[i * 4 + 0] += xv[u] * wv.x;
                acc[i * 4 + 1] += xv[u] * wv.y;
                acc[i * 4 + 2] += xv[u] * wv.z;
                acc[i * 4 + 3] += xv[u] * wv.w;
            }
        }
    }
    bf16x8 r0, r1;
#pragma unroll
    for (int i = 0; i < 16; ++i) {
        int c2 = c2base + q * 16 + i;
        float s = gamma[c2] * rsqrtf(var[c2] + 1e-5f);
        float v = acc[i] * s + (beta[c2] - mean[c2] * s);
        xp[((b * 256 + c2) << 12) + hw] = v;
        if (i < 8) r0[i] = (short)f2b(v); else r1[i - 8] = (short)f2b(v);
    }
    unsigned short* hb = xph + (((b << 12) + hw) << 8) + c2base + q * 16;
    *(bf16x8*)hb = r0;
    *(bf16x8*)(hb + 8) = r1;
}

// ---------------------------------------------------------------------------
// K2: 3x3 offset conv (256 -> 18) via atomicAdd, one 32-channel slice/block.
// grid 2048 x 256: bx = b*512 + h*8 + cs
__global__ __launch_bounds__(256) void k2_off(const float* __restrict__ xp,
                                              const float* __restrict__ offw,
                                              float* __restrict__ off) {
    __shared__ float xl[3 * 32 * 66];
    __shared__ float wl[9 * 18 * 32];
    int t = threadIdx.x;
    int bx = blockIdx.x;
    int b = bx >> 9, h = (bx >> 3) & 63, cs = bx & 7;
    int w = t & 63, jset = t >> 6;
    const int jbase_a[4] = {0, 5, 10, 14};
    const int jcnt_a[4] = {5, 5, 4, 4};
    int jbase = jbase_a[jset], jcnt = jcnt_a[jset];
    float acc[5] = {0.f, 0.f, 0.f, 0.f, 0.f};
    int cbase = cs * 32;

    for (int idx = t; idx < 3 * 32 * 66; idx += 256) {
        int dy = idx / 2112, rem = idx % 2112;
        int c = rem / 66, col = rem % 66;
        int y = h + dy - 1, wc = col - 1;
        float v = 0.f;
        if ((unsigned)y < 64u && (unsigned)wc < 64u)
            v = xp[((b * 256 + cbase + c) << 12) + y * 64 + wc];
        xl[idx] = v;
    }
    for (int idx = t; idx < 18 * 32 * 9; idx += 256) {
        int j = idx / 288, c = (idx / 9) % 32, tap = idx % 9;
        wl[(tap * 18 + j) * 32 + c] = offw[(j * 256 + cbase + c) * 9 + tap];
    }
    __syncthreads();
#pragma unroll
    for (int tap = 0; tap < 9; ++tap) {
        int dy = tap / 3, dx = tap % 3;
        const float* xrow = &xl[dy * 2112 + (w + dx)];
        const float4* wrow = (const float4*)&wl[(tap * 18 + jbase) * 32];
#pragma unroll
        for (int c4 = 0; c4 < 8; ++c4) {
            float xv0 = xrow[(c4 * 4 + 0) * 66];
            float xv1 = xrow[(c4 * 4 + 1) * 66];
            float xv2 = xrow[(c4 * 4 + 2) * 66];
            float xv3 = xrow[(c4 * 4 + 3) * 66];
#pragma unroll
            for (int jj = 0; jj < 5; ++jj) {
                if (jj < jcnt) {
                    float4 wv = wrow[jj * 8 + c4];
                    acc[jj] += xv0 * wv.x + xv1 * wv.y + xv2 * wv.z + xv3 * wv.w;
                }
            }
        }
    }
    for (int jj = 0; jj < 5; ++jj) {
        if (jj < jcnt)
            atomicAdd(&off[((b * 18 + jbase + jj) << 12) + h * 64 + w], acc[jj]);
    }
}

// ---------------------------------------------------------------------------
// K3: deformable sampling (HWC gathers) + bf16 MFMA einsum + SiLU.
// 512 thr = 8 waves; tile 32 px x 256 o; wave tile 32 o x 32 px.
// smp stored in MFMA-FRAGMENT order: [buf][frag F=pt*8+ks][chunk][8 bf16],
// chunk = lane ^ (F&7)  -> conflict-free ds_read_b128 / ds_write_b128.
// Split-stage producer (T14): issue gathers for tap+1 before MFMA(tap),
// bilinear+LDS-write after. launch_bounds (512,4) -> VGPR cap 128.
__global__ __launch_bounds__(512, 4) void k3_dcn(const unsigned short* __restrict__ xph,
                                                 const float* __restrict__ off,
                                                 const unsigned short* __restrict__ wTb,
                                                 float* __restrict__ out) {
    __shared__ int   i00[288], i01[288], i10[288], i11[288];
    __shared__ float w00[288], w01[288], w10[288], w11[288];
    __shared__ unsigned short smp[2][16 * 64 * 8];   // [buf][frag][chunk][8]

    int t = threadIdx.x;
    int orig = blockIdx.x;
    int bx = (orig & 7) * 64 + (orig >> 3);      // XCD-bijective swizzle (512%8==0)
    int b = bx >> 7, h = (bx >> 1) & 63, wh = (bx & 1) * 32;
    int wv = t >> 6, l = t & 63;
    const unsigned short* xb = xph + (b << 20);  // batch base (HWC)

    // phase A: sampling params for 9 taps x 32 px; store loc<<8 (ushort offset)
    if (t < 288) {
        int n = t >> 5, p = t & 31;
        int w = wh + p;
        float oy = off[((b * 18 + n) << 12) + h * 64 + w];
        float ox = off[((b * 18 + n + 9) << 12) + h * 64 + w];
        float py = (float)(h + n / 3 - 1) + oy;
        float px = (float)(w + n % 3 - 1) + ox;
        py = fminf(fmaxf(py, 0.f), 63.f);
        px = fminf(fmaxf(px, 0.f), 63.f);
        float fy = floorf(py), fx = floorf(px);
        int y0 = (int)fy, x0 = (int)fx;
        float wy = py - fy, wx = px - fx;
        int y1 = min(y0 + 1, 63), x1 = min(x0 + 1, 63);
        i00[t] = (y0 * 64 + x0) << 8;  i01[t] = (y0 * 64 + x1) << 8;
        i10[t] = (y1 * 64 + x0) << 8;  i11[t] = (y1 * 64 + x1) << 8;
        w00[t] = (1.f - wy) * (1.f - wx);  w01[t] = (1.f - wy) * wx;
        w10[t] = wy * (1.f - wx);          w11[t] = wy * wx;
    }
    __syncthreads();

    // producer unit u = t + k*512 -> px = u>>5, cg = u&31 (channels cg*8..cg*8+7)
    // dest frag F = (px>>4)*8 + (cg>>2); dest lane = (cg&3)*16 + (px&15)
    bf16x8 g[2][4];                              // in-flight gathers (32 VGPR)

    auto stage_issue = [&](int tap) {
#pragma unroll
        for (int ku = 0; ku < 2; ++ku) {
            int unit = t + ku * 512;
            int px = unit >> 5, cg = unit & 31;
            int sb = tap * 32 + px;
            int c = cg << 3;
            g[ku][0] = *(const bf16x8*)(xb + i00[sb] + c);
            g[ku][1] = *(const bf16x8*)(xb + i01[sb] + c);
            g[ku][2] = *(const bf16x8*)(xb + i10[sb] + c);
            g[ku][3] = *(const bf16x8*)(xb + i11[sb] + c);
        }
    };
    auto stage_write = [&](int tap) {
        int bu = tap & 1;
#pragma unroll
        for (int ku = 0; ku < 2; ++ku) {
            int unit = t + ku * 512;
            int px = unit >> 5, cg = unit & 31;
            int sb = tap * 32 + px;
            float b00 = w00[sb], b01 = w01[sb], b10 = w10[sb], b11 = w11[sb];
            bf16x8 r;
#pragma unroll
            for (int j = 0; j < 8; ++j) {
                float v = b00 * b2f((unsigned short)g[ku][0][j]) +
                          b01 * b2f((unsigned short)g[ku][1][j]) +
                          b10 * b2f((unsigned short)g[ku][2][j]) +
                          b11 * b2f((unsigned short)g[ku][3][j]);
                r[j] = (short)f2b(v);
            }
            int F = (px >> 4) * 8 + (cg >> 2);
            int lane = (cg & 3) * 16 + (px & 15);
            *(bf16x8*)&smp[bu][(F * 64 + (lane ^ (F & 7))) << 3] = r;
        }
    };

    // prologue: fill buffer 0
    stage_issue(0);
    stage_write(0);
    __syncthreads();

    f32x4 acc[2][2];
#pragma unroll
    for (int i = 0; i < 2; ++i)
#pragma unroll
        for (int j = 0; j < 2; ++j) acc[i][j] = (f32x4)0.f;

    int arow = l & 15, areg = l >> 4;            // A: row=o (l&15), k-reg group
    for (int tap = 0; tap < 9; ++tap) {
        if (tap < 8) stage_issue(tap + 1);       // gathers in flight over MFMA
        int bu = tap & 1;
        const unsigned short* wbase =
            wTb + (tap * 256 + wv * 32 + arow) * 256 + areg * 8;
        __builtin_amdgcn_s_setprio(1);
#pragma unroll
        for (int ks = 0; ks < 8; ++ks) {
            bf16x8 a0 = *(const bf16x8*)(wbase + ks * 32);
            bf16x8 a1 = *(const bf16x8*)(wbase + 16 * 256 + ks * 32);
#pragma unroll
            for (int pt = 0; pt < 2; ++pt) {
                int F = pt * 8 + ks;
                bf16x8 bfr = *(const bf16x8*)
                    &smp[bu][(F * 64 + (l ^ (F & 7))) << 3];
                acc[0][pt] = __builtin_amdgcn_mfma_f32_16x16x32_bf16(a0, bfr, acc[0][pt], 0, 0, 0);
                acc[1][pt] = __builtin_amdgcn_mfma_f32_16x16x32_bf16(a1, bfr, acc[1][pt], 0, 0, 0);
            }
        }
        __builtin_amdgcn_s_setprio(0);
        if (tap < 8) stage_write(tap + 1);       // bilinear + LDS write after MFMA
        __syncthreads();
    }

    // epilogue: SiLU + store. D: row(o) = (l>>4)*4+j, col(px) = l&15
#pragma unroll
    for (int ot = 0; ot < 2; ++ot)
#pragma unroll
        for (int pt = 0; pt < 2; ++pt) {
            int px = wh + pt * 16 + (l & 15);
#pragma unroll
            for (int j = 0; j < 4; ++j) {
                int o = wv * 32 + ot * 16 + (l >> 4) * 4 + j;
                float a = acc[ot][pt][j];
                out[((b * 256 + o) << 12) + h * 64 + px] = a / (1.f + expf(-a));
            }
        }
}

// ---------------------------------------------------------------------------
extern "C" void kernel_launch(void* const* d_in, const int* in_sizes, int n_in,
                              void* d_out, int out_size, void* d_ws, size_t ws_size,
                              hipStream_t stream) {
    const float* x     = (const float*)d_in[0];
    const float* pw    = (const float*)d_in[1];
    const float* gamma = (const float*)d_in[2];
    const float* beta  = (const float*)d_in[3];
    const float* mean  = (const float*)d_in[4];
    const float* var   = (const float*)d_in[5];
    const float* offw  = (const float*)d_in[6];
    const float* offb  = (const float*)d_in[7];
    const float* dcn   = (const float*)d_in[8];
    float* ws = (float*)d_ws;
    float* xp  = ws + XP_F;
    float* off = ws + OFF_F;
    unsigned short* xph = (unsigned short*)(ws + XPH_F);
    unsigned short* wTb = (unsigned short*)(ws + WTB_F);
    float* out = (float*)d_out;

    hipLaunchKernelGGL(k0_prep, dim3(2304), dim3(256), 0, stream, dcn, offb, wTb, off);
    hipLaunchKernelGGL(k1_pw_bn, dim3(256, 4), dim3(256), 0, stream,
                       x, pw, gamma, beta, mean, var, xp, xph);
    hipLaunchKernelGGL(k2_off, dim3(2048), dim3(256), 0, stream, xp, offw, off);
    hipLaunchKernelGGL(k3_dcn, dim3(512), dim3(512), 0, stream, xph, off, wTb, out);
}